// Round 13
// baseline (88.404 us; speedup 1.0000x reference)
//
#include <hip/hip_runtime.h>
#include <math.h>

#define N_NODES 50000
#define DEG 16
#define EPSF 1e-5f

typedef unsigned int uint;
typedef unsigned short ushort;
typedef unsigned char uchar;

using bf16x8 = __attribute__((ext_vector_type(8))) short;
using f32x4  = __attribute__((ext_vector_type(4))) float;

__device__ __forceinline__ uint f2bf_rn(float f) {
    uint u = __float_as_uint(f);
    return (u + 0x7FFFu + ((u >> 16) & 1u)) >> 16;
}
__device__ __forceinline__ uint pack2(float a, float b) {
    return f2bf_rn(a) | (f2bf_rn(b) << 16);
}

// ---- VALU-only wave reductions --------------------------------------------
__device__ __forceinline__ float pl32_max(float v) {
#if __has_builtin(__builtin_amdgcn_permlane32_swap)
    auto r = __builtin_amdgcn_permlane32_swap((int)__float_as_uint(v), (int)__float_as_uint(v), false, false);
    return fmaxf(__uint_as_float((uint)r[0]), __uint_as_float((uint)r[1]));
#else
    return fmaxf(v, __shfl_xor(v, 32, 64));
#endif
}
__device__ __forceinline__ float pl16_max(float v) {
#if __has_builtin(__builtin_amdgcn_permlane16_swap)
    auto r = __builtin_amdgcn_permlane16_swap((int)__float_as_uint(v), (int)__float_as_uint(v), false, false);
    return fmaxf(__uint_as_float((uint)r[0]), __uint_as_float((uint)r[1]));
#else
    return fmaxf(v, __shfl_xor(v, 16, 64));
#endif
}
#define DPP_ROR_ADD(v, CTRL) \
    v += __uint_as_float((uint)__builtin_amdgcn_update_dpp(0, (int)__float_as_uint(v), (CTRL), 0xF, 0xF, false))
#define DPP_ROR_MAX(v, CTRL) \
    v = fmaxf(v, __uint_as_float((uint)__builtin_amdgcn_update_dpp(0, (int)__float_as_uint(v), (CTRL), 0xF, 0xF, false)))

// full sum / max within each 16-lane DPP row (all 16 lanes get the result)
__device__ __forceinline__ float red16_sum(float v) {
    DPP_ROR_ADD(v, 0x121); DPP_ROR_ADD(v, 0x122);
    DPP_ROR_ADD(v, 0x124); DPP_ROR_ADD(v, 0x128);
    return v;
}
__device__ __forceinline__ float red16_max(float v) {
    DPP_ROR_MAX(v, 0x121); DPP_ROR_MAX(v, 0x122);
    DPP_ROR_MAX(v, 0x124); DPP_ROR_MAX(v, 0x128);
    return v;
}

// ---- fast hyperbolic helpers ----------------------------------------------
__device__ __forceinline__ float tanh_over_x(float nm) {      // tanh(nm)/nm, nm>0
    float e = __expf(2.f * nm);
    float t = 1.f - __fdividef(2.f, e + 1.f);
    return __fdividef(t, nm);
}
__device__ __forceinline__ float atanh_over_x(float n) {      // atanh(n)/n, 0<n<1
    float l = __logf(__fdividef(1.f + n, 1.f - n));
    return 0.5f * __fdividef(l, n);
}

// ---- int8 decode: 4 ubytes of dw, acc[i] += ubyte_i * rs ------------------
__device__ __forceinline__ void acc4(float* acc, uint dw, float rs) {
    acc[0] = fmaf((float)(dw & 0xffu),         rs, acc[0]);
    acc[1] = fmaf((float)((dw >> 8) & 0xffu),  rs, acc[1]);
    acc[2] = fmaf((float)((dw >> 16) & 0xffu), rs, acc[2]);
    acc[3] = fmaf((float)(dw >> 24),           rs, acc[3]);
}
__device__ __forceinline__ void acc16(float* acc, uint4 r, float rs) {
    acc4(acc + 0, r.x, rs); acc4(acc + 4, r.y, rs);
    acc4(acc + 8, r.z, rs); acc4(acc + 12, r.w, rs);
}

// ---------------------------------------------------------------------------
// K0: prep: W_t[n][k]=bf16(W_in[k][n]); Wo_t[n][k]=bf16(W_out[k][n])
// ---------------------------------------------------------------------------
__global__ __launch_bounds__(256) void k_prep(
    const float* __restrict__ W_in, const float* __restrict__ W_out,
    ushort* __restrict__ W_t, ushort* __restrict__ Wo_t)
{
    const int b = blockIdx.x, t = threadIdx.x;
    if (b < 256) {
        W_t[b * 256 + t] = (ushort)f2bf_rn(W_in[t * 256 + b]);
    } else {
        const int n = b - 256;
        Wo_t[n * 256 + t] = (ushort)f2bf_rn(W_out[t * 128 + n]);
    }
}

// ---------------------------------------------------------------------------
// K0b: projected tables P_i = emb_i @ W_in[k_i : k_i+K_i, :]   (f32 [1024][256])
// ---------------------------------------------------------------------------
__global__ __launch_bounds__(256) void k_projtab(
    const float* __restrict__ emb0, const float* __restrict__ emb1,
    const float* __restrict__ emb2, const ushort* __restrict__ W_t,
    float* __restrict__ P0, float* __restrict__ P1, float* __restrict__ P2)
{
    const int tbl = blockIdx.x / 63;
    const int mt  = blockIdx.x % 63;
    const int m0  = mt * 16;

    const float* eb = (tbl == 0) ? emb0 : (tbl == 1) ? emb1 : emb2;
    float* P        = (tbl == 0) ? P0   : (tbl == 1) ? P1   : P2;
    const int KS      = (tbl == 2) ? 2 : 3;          // k-steps of 32
    const int kstride = (tbl == 2) ? 64 : 96;        // row stride in f32 elems
    const int kofs    = tbl * 96;                    // k offset into W_t rows

    const int lane = threadIdx.x & 63;
    const int w    = threadIdx.x >> 6;
    const int l15  = lane & 15;
    const int lhi  = lane >> 4;

    f32x4 acc[4];
    #pragma unroll
    for (int nf = 0; nf < 4; ++nf) acc[nf] = (f32x4){0.f, 0.f, 0.f, 0.f};

    const int arow = min(m0 + l15, 999);
    const float* Ap  = eb + (size_t)arow * kstride + lhi * 8;
    const ushort* Wp = W_t + (size_t)(w * 64 + l15) * 256 + kofs + lhi * 8;

    for (int kk = 0; kk < KS; ++kk) {
        float4 v0 = *(const float4*)(Ap + kk * 32);
        float4 v1 = *(const float4*)(Ap + kk * 32 + 4);
        union { uint4 u; bf16x8 b; } cv;
        cv.u.x = pack2(v0.x, v0.y); cv.u.y = pack2(v0.z, v0.w);
        cv.u.z = pack2(v1.x, v1.y); cv.u.w = pack2(v1.z, v1.w);
        bf16x8 f = cv.b;
        #pragma unroll
        for (int nf = 0; nf < 4; ++nf) {
            bf16x8 wv = *(const bf16x8*)(Wp + (size_t)nf * 16 * 256 + kk * 32);
            acc[nf] = __builtin_amdgcn_mfma_f32_16x16x32_bf16(wv, f, acc[nf], 0, 0, 0);
        }
    }

    const int m = m0 + l15;
    #pragma unroll
    for (int nf = 0; nf < 4; ++nf)
        *(float4*)&P[(size_t)m * 256 + w * 64 + nf * 16 + lhi * 4] =
            *(float4*)&acc[nf];
}

// ---------------------------------------------------------------------------
// K1: encode: t = P0[x0] + P1[x1] + P2[x2] + b_in; quantize rows to biased-u8
// q1 + rscale1. 16-lane group per node, lane owns 16 cols (64 B).
// ---------------------------------------------------------------------------
__global__ __launch_bounds__(256) void k_encode_gather(
    const int* __restrict__ x,
    const float* __restrict__ P0, const float* __restrict__ P1,
    const float* __restrict__ P2, const float* __restrict__ b_in,
    uchar* __restrict__ q1, float* __restrict__ rscale1)
{
    const int tid = threadIdx.x;
    const int gi  = tid >> 4;
    const int p   = tid & 15;
    const int v   = blockIdx.x * 16 + gi;      // 50000 = 3125*16, exact

    const int x0 = x[v * 3 + 0];
    const int x1 = x[v * 3 + 1];
    const int x2 = x[v * 3 + 2];

    const float* p0 = P0 + (size_t)x0 * 256 + p * 16;
    const float* p1 = P1 + (size_t)x1 * 256 + p * 16;
    const float* p2 = P2 + (size_t)x2 * 256 + p * 16;
    const float* bp = b_in + p * 16;

    float tv[16];
    #pragma unroll
    for (int u = 0; u < 4; ++u) {
        float4 a = *(const float4*)(p0 + u * 4);
        float4 c = *(const float4*)(p1 + u * 4);
        float4 d = *(const float4*)(p2 + u * 4);
        float4 bb = *(const float4*)(bp + u * 4);
        tv[u * 4 + 0] = a.x + c.x + d.x + bb.x;
        tv[u * 4 + 1] = a.y + c.y + d.y + bb.y;
        tv[u * 4 + 2] = a.z + c.z + d.z + bb.z;
        tv[u * 4 + 3] = a.w + c.w + d.w + bb.w;
    }

    float lm = 0.f;
    #pragma unroll
    for (int i = 0; i < 16; ++i) lm = fmaxf(lm, fabsf(tv[i]));
    float rm = fmaxf(red16_max(lm), 1e-20f);
    const float qs = __fdividef(127.f, rm);

    uint d[4];
    #pragma unroll
    for (int k = 0; k < 4; ++k) {
        uint b0 = (uint)(int)rintf(fmaf(tv[4 * k + 0], qs, 128.f));
        uint b1 = (uint)(int)rintf(fmaf(tv[4 * k + 1], qs, 128.f));
        uint b2 = (uint)(int)rintf(fmaf(tv[4 * k + 2], qs, 128.f));
        uint b3 = (uint)(int)rintf(fmaf(tv[4 * k + 3], qs, 128.f));
        d[k] = b0 | (b1 << 8) | (b2 << 16) | (b3 << 24);
    }
    uint4 o; o.x = d[0]; o.y = d[1]; o.z = d[2]; o.w = d[3];
    *(uint4*)&q1[(size_t)v * 256 + p * 16] = o;
    if (p == 0) rscale1[v] = rm * (1.f / 127.f);
}

// ---------------------------------------------------------------------------
// K2: FUSED hat1 + fc_out-projection, forced-MLP gather:
//   Phase A: issue ALL 17 row loads + 17 scale loads, sched_barrier(0),
//            then decode. z = mean_17; l2 = log0(relu(exp0(z))) -> LDS tile.
//   Phase B: y = l2_tile @ W_out + b_out (MFMA), quantize per-row -> qy.
// launch_bounds(256,3): VGPR cap ~170 so all 17 uint4 stay live, no spill.
// ---------------------------------------------------------------------------
__global__ __launch_bounds__(256, 3) void k_hat1_fc(
    const uchar* __restrict__ q1, const float* __restrict__ rscale1,
    const int* __restrict__ src,
    const ushort* __restrict__ Wo_t, const float* __restrict__ b_out,
    uchar* __restrict__ qy, float* __restrict__ rscale_y)
{
    __shared__ int lsrc[256];
    __shared__ ushort T[16][264];        // 16 l2 rows, +8 pad
    __shared__ float smaxq[4][16];

    const int tid = threadIdx.x;
    const int gi  = tid >> 4;           // node within block
    const int p   = tid & 15;           // 16-col chunk
    const int vb  = blockIdx.x * 16;
    const int v   = vb + gi;
    const int base = gi << 4;

    // self row load issues before lsrc is even needed
    uint4 rself = *(const uint4*)(q1 + ((size_t)v << 8) + p * 16);
    float sself = rscale1[v];

    lsrc[tid] = src[(size_t)vb * DEG + tid];
    __syncthreads();

    // ---- phase A: issue all neighbor loads, then barrier, then decode ----
    uint4 ra[16]; float sa[16];
    #pragma unroll
    for (int j = 0; j < 16; ++j) {
        const int s = lsrc[base | j];
        ra[j] = *(const uint4*)(q1 + ((size_t)s << 8) + p * 16);
        sa[j] = rscale1[s];
    }
    __builtin_amdgcn_sched_barrier(0);   // nothing moves across: all loads issued

    float acc[16];
    #pragma unroll
    for (int i = 0; i < 16; i++) acc[i] = 0.f;
    float srs = sself;
    acc16(acc, rself, sself);
    #pragma unroll
    for (int j = 0; j < 16; ++j) { srs += sa[j]; acc16(acc, ra[j], sa[j]); }

    const float inv = 1.f / (float)(DEG + 1);
    const float bias = 128.f * srs;
    float rz[16], ss = 0.f, ssp = 0.f;
    #pragma unroll
    for (int i = 0; i < 16; i++) {
        float z = (acc[i] - bias) * inv;
        ss += z * z;
        rz[i] = fmaxf(z, 0.f);
        ssp += rz[i] * rz[i];
    }
    ss  = red16_sum(ss);
    ssp = red16_sum(ssp);

    float se = tanh_over_x(fmaxf(sqrtf(ss), EPSF));
    float nh = se * sqrtf(ssp);
    float nc = fminf(fmaxf(nh, EPSF), 1.f - EPSF);
    float c  = atanh_over_x(nc) * se;

    uint4 o1, o2;
    o1.x = pack2(c * rz[0],  c * rz[1]);
    o1.y = pack2(c * rz[2],  c * rz[3]);
    o1.z = pack2(c * rz[4],  c * rz[5]);
    o1.w = pack2(c * rz[6],  c * rz[7]);
    o2.x = pack2(c * rz[8],  c * rz[9]);
    o2.y = pack2(c * rz[10], c * rz[11]);
    o2.z = pack2(c * rz[12], c * rz[13]);
    o2.w = pack2(c * rz[14], c * rz[15]);
    *(uint4*)&T[gi][p * 16]     = o1;
    *(uint4*)&T[gi][p * 16 + 8] = o2;
    __syncthreads();

    // ---- phase B: y = T @ W_out + b_out, quantize -> qy ----
    const int lane = tid & 63;
    const int w    = tid >> 6;
    const int l15  = lane & 15;          // node
    const int lhi  = lane >> 4;

    f32x4 facc[2];
    facc[0] = (f32x4){0.f, 0.f, 0.f, 0.f};
    facc[1] = (f32x4){0.f, 0.f, 0.f, 0.f};

    const ushort* Wp = Wo_t + (size_t)(w * 2 * 16 + l15) * 256 + lhi * 8;

    for (int kk = 0; kk < 8; ++kk) {
        bf16x8 f = *(const bf16x8*)&T[l15][kk * 32 + lhi * 8];
        #pragma unroll
        for (int nf = 0; nf < 2; ++nf) {
            bf16x8 wv = *(const bf16x8*)(Wp + (size_t)nf * 16 * 256 + kk * 32);
            facc[nf] = __builtin_amdgcn_mfma_f32_16x16x32_bf16(wv, f, facc[nf], 0, 0, 0);
        }
    }

    float lm = 0.f;
    #pragma unroll
    for (int nf = 0; nf < 2; ++nf) {
        float4 bb = *(const float4*)&b_out[(w * 2 + nf) * 16 + lhi * 4];
        facc[nf][0] += bb.x; facc[nf][1] += bb.y;
        facc[nf][2] += bb.z; facc[nf][3] += bb.w;
        lm = fmaxf(lm, fmaxf(fmaxf(fabsf(facc[nf][0]), fabsf(facc[nf][1])),
                             fmaxf(fabsf(facc[nf][2]), fabsf(facc[nf][3]))));
    }
    lm = pl16_max(lm);
    lm = pl32_max(lm);
    if (lhi == 0) smaxq[w][l15] = lm;
    __syncthreads();

    float rm = fmaxf(fmaxf(smaxq[0][l15], smaxq[1][l15]),
                     fmaxf(smaxq[2][l15], smaxq[3][l15]));
    rm = fmaxf(rm, 1e-20f);
    const float qs = __fdividef(127.f, rm);
    const int node = vb + l15;

    #pragma unroll
    for (int nf = 0; nf < 2; ++nf) {
        uint b0 = (uint)(int)rintf(fmaf(facc[nf][0], qs, 128.f));
        uint b1 = (uint)(int)rintf(fmaf(facc[nf][1], qs, 128.f));
        uint b2 = (uint)(int)rintf(fmaf(facc[nf][2], qs, 128.f));
        uint b3 = (uint)(int)rintf(fmaf(facc[nf][3], qs, 128.f));
        *(uint*)&qy[(size_t)node * 128 + (w * 2 + nf) * 16 + lhi * 4] =
            b0 | (b1 << 8) | (b2 << 16) | (b3 << 24);
    }
    if (tid < 16) rscale_y[vb + tid] = rm * (1.f / 127.f);
}

// ---------------------------------------------------------------------------
// K3: out = exp0(mean_17(qy rows))   (128 B rows, biased u8)
// Forced-MLP: all 17 loads issued before decode via sched_barrier(0).
// ---------------------------------------------------------------------------
__global__ __launch_bounds__(256, 4) void k_hat2_q(
    const uchar* __restrict__ qy, const float* __restrict__ rscale_y,
    const int* __restrict__ src, float* __restrict__ out)
{
    __shared__ int lsrc[256];
    const int tid = threadIdx.x;
    const int gi  = tid >> 4;
    const int p   = tid & 15;           // 8 B chunk within 128 B row
    const int vb  = blockIdx.x * 16;
    const int v   = vb + gi;
    const int base = gi << 4;

    uint2 rself = *(const uint2*)(qy + ((size_t)v << 7) + p * 8);
    float sself = rscale_y[v];

    lsrc[tid] = src[(size_t)vb * DEG + tid];
    __syncthreads();

    uint2 r[16]; float sv[16];
    #pragma unroll
    for (int j = 0; j < 16; ++j) {
        const int s = lsrc[base | j];
        r[j] = *(const uint2*)(qy + ((size_t)s << 7) + p * 8);
        sv[j] = rscale_y[s];
    }
    __builtin_amdgcn_sched_barrier(0);

    float acc[8];
    #pragma unroll
    for (int i = 0; i < 8; i++) acc[i] = 0.f;
    float srs = sself;
    acc4(acc + 0, rself.x, sself);
    acc4(acc + 4, rself.y, sself);
    #pragma unroll
    for (int j = 0; j < 16; ++j) {
        srs += sv[j];
        acc4(acc + 0, r[j].x, sv[j]);
        acc4(acc + 4, r[j].y, sv[j]);
    }

    const float inv = 1.f / (float)(DEG + 1);
    const float bias = 128.f * srs;
    float z[8], ss = 0.f;
    #pragma unroll
    for (int i = 0; i < 8; i++) {
        z[i] = (acc[i] - bias) * inv;
        ss += z[i] * z[i];
    }
    ss = red16_sum(ss);

    float se = tanh_over_x(fmaxf(sqrtf(ss), EPSF));

    float4 o0, o1;
    o0.x = se * z[0]; o0.y = se * z[1]; o0.z = se * z[2]; o0.w = se * z[3];
    o1.x = se * z[4]; o1.y = se * z[5]; o1.z = se * z[6]; o1.w = se * z[7];
    float* row = out + (size_t)v * 128 + p * 8;
    *(float4*)row = o0;
    *(float4*)(row + 4) = o1;
}

extern "C" void kernel_launch(void* const* d_in, const int* in_sizes, int n_in,
                              void* d_out, int out_size, void* d_ws, size_t ws_size,
                              hipStream_t stream) {
    const int*   x     = (const int*)  d_in[0];
    const float* emb0  = (const float*)d_in[1];
    const float* emb1  = (const float*)d_in[2];
    const float* emb2  = (const float*)d_in[3];
    const float* W_in  = (const float*)d_in[4];
    const float* b_in  = (const float*)d_in[5];
    const float* W_out = (const float*)d_in[6];
    const float* b_out = (const float*)d_in[7];
    const int*   src0  = (const int*)  d_in[8];
    const int*   src1  = (const int*)  d_in[10];
    float* out = (float*)d_out;

    uchar*  q1       = (uchar*)d_ws;                            // 12.8 MB
    uchar*  qy       = q1 + (size_t)N_NODES * 256;              // 6.4 MB
    float*  rscale1  = (float*)(qy + (size_t)N_NODES * 128);    // 200 KB
    float*  rscale_y = rscale1 + N_NODES;                       // 200 KB
    ushort* W_t      = (ushort*)(rscale_y + N_NODES);           // 128 KB
    ushort* Wo_t     = W_t + 256 * 256;                         // 64 KB
    float*  P0       = (float*)(Wo_t + 128 * 256);              // 1 MB (1024 rows)
    float*  P1       = P0 + 1024 * 256;                         // 1 MB
    float*  P2       = P1 + 1024 * 256;                         // 1 MB

    k_prep<<<384, 256, 0, stream>>>(W_in, W_out, W_t, Wo_t);
    k_projtab<<<189, 256, 0, stream>>>(emb0, emb1, emb2, W_t, P0, P1, P2);
    k_encode_gather<<<N_NODES / 16, 256, 0, stream>>>(x, P0, P1, P2, b_in, q1, rscale1);
    k_hat1_fc<<<N_NODES / 16, 256, 0, stream>>>(q1, rscale1, src0, Wo_t, b_out, qy, rscale_y);
    k_hat2_q<<<N_NODES / 16, 256, 0, stream>>>(qy, rscale_y, src1, out);
}